// Round 2
// 329.268 us; speedup vs baseline: 1.0716x; 1.0716x over previous
//
#include <hip/hip_runtime.h>
#include <hip/hip_bf16.h>

// HAN forward, del-branch only (add-branch _group output is unused in the reference).
// Inputs f32 / int32; output f32 [4096,256]. h and out_* stored bf16.
//
// R13 (resubmit; previous round hit GPUAcquisitionTimeout, no data):
//  - gemm_h3: DRAM-page-locality rewrite of the projection GEMM.
//    Old gemm_h2 fetched X in 128-B-per-row K-chunks across ~49k concurrent row
//    streams -> every access a DRAM page activation -> hard 1.47 TB/s ceiling
//    (measured; ~512 banks / 45ns * 128B = 1.46 TB/s).
//    New: BM=64 x BN=256 (single X pass), A reg-staged in K-chunks of 128 f32 =
//    512-B contiguous per row per wave-instruction, cvt->bf16 into XOR-swizzled
//    2x16KB LDS chunk dbuf. B keeps global_load_lds triple-buffer with counted
//    vmcnt (never drained mid-loop). 80 KB LDS -> 2 blocks/CU (16 waves).
//  - node_scores fused into gemm epilogue (both heads in-block now).
//  - edge_gather2: 2-edge unroll (2 independent gather chains in flight).

typedef unsigned short u16;
typedef __attribute__((ext_vector_type(8))) __bf16 bf16x8;
typedef __attribute__((ext_vector_type(4))) float f32x4;
typedef const __attribute__((address_space(1))) unsigned int* gu32p;
typedef __attribute__((address_space(3))) unsigned int* su32p;

__device__ inline float bf2f(u16 u) {
    union { unsigned int i; float f; } c; c.i = ((unsigned int)u) << 16; return c.f;
}
__device__ inline u16 f2bf(float f) {  // round-to-nearest-even
    union { float f; unsigned int i; } c; c.f = f;
    return (u16)((c.i + 0x7fffu + ((c.i >> 16) & 1u)) >> 16);
}
__device__ inline bf16x8 cvt8(f32x4 a, f32x4 b) {
    bf16x8 r;
    r[0] = (__bf16)a[0]; r[1] = (__bf16)a[1]; r[2] = (__bf16)a[2]; r[3] = (__bf16)a[3];
    r[4] = (__bf16)b[0]; r[5] = (__bf16)b[1]; r[6] = (__bf16)b[2]; r[7] = (__bf16)b[3];
    return r;
}
__device__ inline float fast_tanh(float x) {
    x = fminf(9.f, fmaxf(-9.f, x));
    float t = __expf(2.f * x);
    return (t - 1.f) / (t + 1.f);
}

// ---------------- 0. prep: W/kW f32->bf16 cvt + degree histogram (one dispatch) -----
__global__ __launch_bounds__(256) void prep_count(const float* __restrict__ W0, u16* __restrict__ wb0,
                                                  const float* __restrict__ W1, u16* __restrict__ wb1,
                                                  const float* __restrict__ kW, u16* __restrict__ kwb,
                                                  const int* __restrict__ eiA, int* __restrict__ cntA,
                                                  const int* __restrict__ eiB, int* __restrict__ cntB, int E) {
    int b = blockIdx.x;
    if (b < 224) {                        // 57344 chunks of 8 = W0|W1|kW exactly
        int idx = b * 256 + threadIdx.x;
        const float* s; u16* d; int i;
        if (idx < 24576)      { s = W0; d = wb0; i = idx; }
        else if (idx < 49152) { s = W1; d = wb1; i = idx - 24576; }
        else                  { s = kW; d = kwb; i = idx - 49152; }
        int e = i * 8;
        *(bf16x8*)(d + e) = cvt8(*(const f32x4*)(s + e), *(const f32x4*)(s + e + 4));
    } else {
        int idx = (b - 224) * 256 + threadIdx.x;
        int which = idx >= E;
        int e = idx - (which ? E : 0);
        if (e >= E) return;
        const int* ei = which ? eiB : eiA;
        int* cnt = which ? cntB : cntA;
        atomicAdd(&cnt[ei[E + e]], 1);
    }
}

// ---------------- 1. h = X @ W^T + b (+ fused attention-score dots) -----------------
// BM=64 BN=256 (single X pass); 626 blocks x 512 threads (8 waves, each 32x64).
// A: reg-staged 512-B-per-row K-chunks (128 f32), cvt->bf16, XOR-swizzled LDS dbuf.
// B: global_load_lds triple-buffer, stored-swizzled, counted vmcnt (no mid-loop drain).
__global__ __launch_bounds__(512, 4) void gemm_h3(
    const float* __restrict__ X0, const u16* __restrict__ Wb0,
    const float* __restrict__ b0, u16* __restrict__ H0,
    const float* __restrict__ X1, const u16* __restrict__ Wb1,
    const float* __restrict__ b1, u16* __restrict__ H1,
    const float* __restrict__ w_ads, const float* __restrict__ w_add,
    const float* __restrict__ w_dds, const float* __restrict__ w_ddd,
    float* __restrict__ as_ad, float* __restrict__ ad_ad,
    float* __restrict__ as_dd, float* __restrict__ ad_dd, int M) {
    // LDS map (u16 units): A chunk dbuf 2 x 8192 (each 64 rows x 128 bf16, swizzled)
    //                      B slots 3 x 8192 at +16384 (each 256 rows x 32 bf16)
    __shared__ u16 lds[40960];           // 80 KB total -> 2 blocks/CU
    int id = blockIdx.x;
    int which = id >= 313;
    int bm = which ? id - 313 : id;
    const float* X = which ? X1 : X0;
    const u16* Wb = which ? Wb1 : Wb0;
    const float* bias = which ? b1 : b0;
    u16* H = which ? H1 : H0;

    int tid = threadIdx.x;
    int w = tid >> 6, lane = tid & 63;
    int wrow = w & 1, wcol = w >> 1;     // wave tile: rows wrow*32..+32, cols wcol*64..+64
    int row16 = lane & 15, quad = lane >> 4;

// B tile kt -> slot: per wave 2 DMAs, 16 rows x 32 K bf16 each (stored-swizzled)
#define ISSUE_B(kt, slot) { \
    _Pragma("unroll") \
    for (int j = 0; j < 2; ++j) { \
        int rloc = (w * 2 + j) * 16 + (lane >> 2); \
        int cc = (lane & 3) ^ ((rloc >> 1) & 3); \
        const u16* gp = Wb + (size_t)rloc * 768 + (kt) * 32 + cc * 8; \
        u16* lp = lds + 16384 + (slot) * 8192 + (w * 2 + j) * 512; \
        __builtin_amdgcn_global_load_lds((gu32p)(const void*)gp, (su32p)(void*)lp, 16, 0, 0); \
    } }

// A chunk c: 64 rows x 128 f32; each wave-instruction covers 2 rows x 512 B contiguous
#define ALOAD(c, ar) { \
    _Pragma("unroll") \
    for (int i = 0; i < 4; ++i) { \
        int idx = i * 512 + tid; \
        int row = idx >> 5, col4 = idx & 31; \
        int rg = bm * 64 + row; if (rg > M - 1) rg = M - 1; \
        ar[i] = *(const f32x4*)(X + (size_t)rg * 768 + (c) * 128 + col4 * 4); \
    } }

// cvt->bf16 and XOR-swizzled store into A chunk buffer (c&1)
#define AWRITE(c, ar) { \
    _Pragma("unroll") \
    for (int i = 0; i < 4; ++i) { \
        int idx = i * 512 + tid; \
        int row = idx >> 5, col4 = idx & 31; \
        int off = ((c) & 1) * 8192 + row * 128 + (((col4 >> 1) ^ (row & 7)) << 3) + ((col4 & 1) << 2); \
        ushort4 v; v.x = f2bf(ar[i][0]); v.y = f2bf(ar[i][1]); v.z = f2bf(ar[i][2]); v.w = f2bf(ar[i][3]); \
        *(ushort4*)(lds + off) = v; \
    } }

#define STEP(ks) { \
    const int ksl = (ks) & 3, buf = ((ks) >> 2) & 1, slot = (ks) % 3; \
    bf16x8 af[2], bv[4]; \
    _Pragma("unroll") \
    for (int mi = 0; mi < 2; ++mi) { \
        int r = wrow * 32 + mi * 16 + row16; \
        af[mi] = *(const bf16x8*)(lds + buf * 8192 + r * 128 + (((ksl * 4 + quad) ^ (r & 7)) << 3)); \
    } \
    _Pragma("unroll") \
    for (int ni = 0; ni < 4; ++ni) { \
        int r = wcol * 64 + ni * 16 + row16; \
        bv[ni] = *(const bf16x8*)(lds + 16384 + slot * 8192 + r * 32 + ((quad ^ ((r >> 1) & 3)) << 3)); \
    } \
    _Pragma("unroll") \
    for (int mi = 0; mi < 2; ++mi) \
        _Pragma("unroll") \
        for (int ni = 0; ni < 4; ++ni) \
            acc[mi][ni] = __builtin_amdgcn_mfma_f32_16x16x32_bf16(af[mi], bv[ni], acc[mi][ni], 0, 0, 0); \
}

    f32x4 a0[4], a1[4];
    // prologue: B0,B1 DMAs; A chunks 0,1 loads; write chunk 0.
    ISSUE_B(0, 0)
    ISSUE_B(1, 1)
    ALOAD(0, a0)
    ALOAD(1, a1)
    asm volatile("s_waitcnt vmcnt(4)" ::: "memory");     // a0 done (drains B0,B1 too)
    AWRITE(0, a0)
    asm volatile("s_waitcnt lgkmcnt(0)" ::: "memory");
    asm volatile("s_barrier" ::: "memory");

    f32x4 acc[2][4] = {};
#pragma unroll
    for (int ks = 0; ks < 24; ++ks) {
        if (ks > 0) {
            // wait table (instruction-count vmcnt; B(ks) must be complete).
            // outstanding worst case after B(ks): <=6 instrs, so vmcnt(6) always safe;
            // tighter values drain finished A-loads before their AWRITE.
            const int wv = (ks == 23) ? 0 : (ks >= 17) ? 2 : ((ks & 2) ? 6 : 2);
            if (wv == 0)      asm volatile("s_waitcnt vmcnt(0) lgkmcnt(0)" ::: "memory");
            else if (wv == 2) asm volatile("s_waitcnt vmcnt(2) lgkmcnt(0)" ::: "memory");
            else              asm volatile("s_waitcnt vmcnt(6) lgkmcnt(0)" ::: "memory");
            asm volatile("s_barrier" ::: "memory");
        }
        if (ks < 22) ISSUE_B(ks + 2, (ks + 2) % 3)
        if (ks == 0) {
            asm volatile("s_waitcnt vmcnt(2)" ::: "memory"); // a1 done (B2 stays in flight)
            AWRITE(1, a1)
        } else if ((ks & 3) == 0 && ks <= 16) {
            AWRITE(ks / 4 + 1, a0)       // ks=4,8,12,16 -> chunks 2..5
        }
        if ((ks & 3) == 1 && ks <= 13) ALOAD(ks / 4 + 2, a0)  // ks=1,5,9,13 -> chunks 2..5
        STEP(ks)
    }
#undef ISSUE_B
#undef ALOAD
#undef AWRITE
#undef STEP

    // ---- epilogue: acc -> LDS bf16, coalesced store + fused att-score dots ----
    __syncthreads();
    u16* eps = lds;                      // 64 x 264 u16 = 33.8 KB
    const int SE2 = 264;
#pragma unroll
    for (int mi = 0; mi < 2; ++mi)
#pragma unroll
        for (int ni = 0; ni < 4; ++ni) {
            int col = wcol * 64 + ni * 16 + row16;
            float bvv = bias[col];
#pragma unroll
            for (int r = 0; r < 4; ++r)
                eps[(wrow * 32 + mi * 16 + quad * 4 + r) * SE2 + col] = f2bf(acc[mi][ni][r] + bvv);
        }
    __syncthreads();
    int mlim = M - bm * 64;
    int c0 = (tid & 31) * 8;             // 8 cols of the 256-col row; head = c0>>7
    int hh = c0 >> 7;
    float wv0[8], wv1[8], wv2[8];
    const float* att0 = which ? w_add : w_ads;
#pragma unroll
    for (int j = 0; j < 8; ++j) {
        wv0[j] = att0[c0 + j];
        wv1[j] = w_dds[c0 + j];
        wv2[j] = w_ddd[c0 + j];
    }
#pragma unroll
    for (int p = 0; p < 4; ++p) {
        int row = p * 16 + (tid >> 5);
        union { uint4 q; u16 s[8]; } v;
        v.q = *(const uint4*)(eps + row * SE2 + c0);
        if (row < mlim)
            *(uint4*)(H + (size_t)(bm * 64 + row) * 256 + c0) = v.q;
        float d0 = 0.f, d1 = 0.f, d2 = 0.f;
#pragma unroll
        for (int j = 0; j < 8; ++j) {
            float hv = bf2f(v.s[j]);
            d0 += hv * wv0[j];
            if (which) { d1 += hv * wv1[j]; d2 += hv * wv2[j]; }
        }
#pragma unroll
        for (int off = 8; off >= 1; off >>= 1) {
            d0 += __shfl_down(d0, off, 16);
            if (which) { d1 += __shfl_down(d1, off, 16); d2 += __shfl_down(d2, off, 16); }
        }
        if ((tid & 15) == 0 && row < mlim) {
            int n = bm * 64 + row;
            if (!which) {
                unsafeAtomicAdd(&as_ad[n * 2 + hh], d0);
            } else {
                unsafeAtomicAdd(&ad_ad[n * 2 + hh], d0);
                unsafeAtomicAdd(&as_dd[n * 2 + hh], d1);
                unsafeAtomicAdd(&ad_dd[n * 2 + hh], d2);
            }
        }
    }
}

// ---------------- 3b. exclusive scan, int4-blocked ----------------------------------
__global__ __launch_bounds__(1024) void scan_two(const int* __restrict__ cntA, int* __restrict__ offA,
                                                 const int* __restrict__ cntB, int* __restrict__ offB, int n) {
    const int* cnt = blockIdx.x ? cntB : cntA;
    int* off = blockIdx.x ? offB : offA;
    __shared__ int wsum[16];
    __shared__ int woff[16];
    __shared__ int tot_s;
    __shared__ int carry_s;
    int tid = threadIdx.x, wid = tid >> 6, lane = tid & 63;
    if (tid == 0) carry_s = 0;
    __syncthreads();
    for (int base = 0; base < n; base += 4096) {
        int i = base + tid * 4;
        int v0 = (i + 0 < n) ? cnt[i + 0] : 0;
        int v1 = (i + 1 < n) ? cnt[i + 1] : 0;
        int v2 = (i + 2 < n) ? cnt[i + 2] : 0;
        int v3 = (i + 3 < n) ? cnt[i + 3] : 0;
        int s0 = v0, s1 = s0 + v1, s2 = s1 + v2, s3 = s2 + v3;
        int x = s3;
#pragma unroll
        for (int d = 1; d < 64; d <<= 1) {
            int t = __shfl_up(x, d, 64);
            if (lane >= d) x += t;
        }
        if (lane == 63) wsum[wid] = x;
        __syncthreads();
        if (wid == 0) {
            int s = (lane < 16) ? wsum[lane] : 0;
#pragma unroll
            for (int d = 1; d < 16; d <<= 1) {
                int t = __shfl_up(s, d, 64);
                if (lane >= d) s += t;
            }
            if (lane < 16) woff[lane] = s - wsum[lane];
            if (lane == 15) tot_s = s;
        }
        __syncthreads();
        int basev = carry_s + woff[wid] + (x - s3);
        if (i + 0 < n) off[i + 0] = basev;
        if (i + 1 < n) off[i + 1] = basev + s0;
        if (i + 2 < n) off[i + 2] = basev + s1;
        if (i + 3 < n) off[i + 3] = basev + s2;
        __syncthreads();
        if (tid == 0) carry_s += tot_s;
    }
    __syncthreads();
    if (tid == 0) off[n] = carry_s;
}

// ---------------- 3c. fill CSR src lists, both edge sets ----------------------------
__global__ __launch_bounds__(256) void fill_csr2(const int* __restrict__ eiA, const int* __restrict__ offA,
                                                 int* __restrict__ curA, int* __restrict__ srcsA,
                                                 const int* __restrict__ eiB, const int* __restrict__ offB,
                                                 int* __restrict__ curB, int* __restrict__ srcsB, int E) {
    int idx = blockIdx.x * 256 + threadIdx.x;
    int which = idx >= E;
    int e = idx - (which ? E : 0);
    if (e >= E) return;
    const int* ei = which ? eiB : eiA;
    const int* off = which ? offB : offA;
    int* cursor = which ? curB : curA;
    int* srcs = which ? srcsB : srcsA;
    int s = ei[e], d = ei[E + e];
    int slot = off[d] + atomicAdd(&cursor[d], 1);
    srcs[slot] = s;
}

// ---------------- 4. gather: one wave per dst node; 2-edge unroll -------------------
__global__ __launch_bounds__(256) void edge_gather2(const int* __restrict__ offA, const int* __restrict__ srcsA,
                                                    const float* __restrict__ asA, const float* __restrict__ adA,
                                                    const u16* __restrict__ hA, u16* __restrict__ outA,
                                                    const int* __restrict__ offB, const int* __restrict__ srcsB,
                                                    const float* __restrict__ asB, const float* __restrict__ adB,
                                                    const u16* __restrict__ hB, u16* __restrict__ outB, int N) {
    int gid = blockIdx.x * 256 + threadIdx.x;
    int dall = gid >> 6;
    int which = dall >= N;
    int d = dall - (which ? N : 0);
    if (d >= N) return;
    const int* off = which ? offB : offA;
    const int* srcs = which ? srcsB : srcsA;
    const float* a_src = which ? asB : asA;
    const float* a_dst = which ? adB : adA;
    const u16* h = which ? hB : hA;
    u16* out = which ? outB : outA;
    int lane = gid & 63;
    int hh = lane >> 5;
    int f = lane * 4;
    float ad0 = a_dst[d * 2 + hh];
    int beg = off[d], end = off[d + 1];
    float4 acc = {0.f, 0.f, 0.f, 0.f};
    float S = 0.f;
    int p = beg;
    for (; p + 2 <= end; p += 2) {       // two independent gather chains in flight
        int s0 = srcs[p], s1 = srcs[p + 1];
        ushort4 x0 = *(const ushort4*)(h + (size_t)s0 * 256 + f);
        ushort4 x1 = *(const ushort4*)(h + (size_t)s1 * 256 + f);
        float v0 = a_src[s0 * 2 + hh] + ad0;
        float v1 = a_src[s1 * 2 + hh] + ad0;
        v0 = v0 > 0.f ? v0 : 0.2f * v0;
        v1 = v1 > 0.f ? v1 : 0.2f * v1;
        float e0 = __expf(v0), e1 = __expf(v1);
        S += e0 + e1;
        acc.x += e0 * bf2f(x0.x) + e1 * bf2f(x1.x);
        acc.y += e0 * bf2f(x0.y) + e1 * bf2f(x1.y);
        acc.z += e0 * bf2f(x0.z) + e1 * bf2f(x1.z);
        acc.w += e0 * bf2f(x0.w) + e1 * bf2f(x1.w);
    }
    if (p < end) {
        int s0 = srcs[p];
        ushort4 x0 = *(const ushort4*)(h + (size_t)s0 * 256 + f);
        float v0 = a_src[s0 * 2 + hh] + ad0;
        v0 = v0 > 0.f ? v0 : 0.2f * v0;
        float e0 = __expf(v0);
        S += e0;
        acc.x += e0 * bf2f(x0.x);
        acc.y += e0 * bf2f(x0.y);
        acc.z += e0 * bf2f(x0.z);
        acc.w += e0 * bf2f(x0.w);
    }
    float inv = 1.f / (S + 1e-16f);
    ushort4 o = {f2bf(acc.x * inv), f2bf(acc.y * inv), f2bf(acc.z * inv), f2bf(acc.w * inv)};
    *(ushort4*)(out + (size_t)d * 256 + f) = o;
}

// ---------------- 5. semantic scores; A bf16, kW pre-converted bf16 -----------------
#define SK 264
__global__ __launch_bounds__(256) void kgemm_score2(const u16* __restrict__ outA,
                                                    const u16* __restrict__ outB,
                                                    const u16* __restrict__ kwb,
                                                    const float* __restrict__ kb,
                                                    const float* __restrict__ qv,
                                                    float* __restrict__ score) {
    __shared__ u16 Bs[128 * SK];          // 66 KB
    __shared__ float red[4];
    int slot = blockIdx.x >> 8;           // 0..1
    int b = blockIdx.x & 255;
    const u16* outm = slot ? outB : outA;
    int bn = b & 1;
    int bidx = b >> 1;                    // 0..127
    int tid = threadIdx.x;
    int w = tid >> 6, lane = tid & 63;
    int row16 = lane & 15, quad = lane >> 4;

#pragma unroll
    for (int i = 0; i < 16; ++i) {
        int c = tid + 256 * i;
        int r = c >> 5, col8 = (c & 31) * 8;
        *(bf16x8*)(Bs + r * SK + col8) = *(const bf16x8*)(kwb + (size_t)(bn * 128 + r) * 256 + col8);
    }
    __syncthreads();

    float kb0 = kb[bn * 128 + w * 32 + row16];
    float qn0 = qv[bn * 128 + w * 32 + row16];
    float kb1 = kb[bn * 128 + w * 32 + 16 + row16];
    float qn1 = qv[bn * 128 + w * 32 + 16 + row16];
    const u16* b0 = Bs + (w * 32 + row16) * SK + quad * 8;
    const u16* b1 = Bs + (w * 32 + 16 + row16) * SK + quad * 8;

    union U { uint4 q; u16 s[8]; bf16x8 v; };
    float p = 0.f;
    for (int mt = bidx; mt < 1250; mt += 128) {
        const u16* arow = outm + (size_t)(mt * 16 + row16) * 256 + quad * 8;
        U a[8];
#pragma unroll
        for (int s8 = 0; s8 < 8; ++s8) a[s8].q = *(const uint4*)(arow + s8 * 32);
        f32x4 acc0 = {0.f,0.f,0.f,0.f}, acc1 = {0.f,0.f,0.f,0.f};
#pragma unroll
        for (int s8 = 0; s8 < 8; ++s8) {
#pragma unroll
            for (int j = 0; j < 8; ++j)       // relu in bf16 domain
                if (a[s8].s[j] & 0x8000u) a[s8].s[j] = 0;
            bf16x8 bf0 = *(const bf16x8*)(b0 + s8 * 32);
            bf16x8 bf1 = *(const bf16x8*)(b1 + s8 * 32);
            acc0 = __builtin_amdgcn_mfma_f32_16x16x32_bf16(a[s8].v, bf0, acc0, 0, 0, 0);
            acc1 = __builtin_amdgcn_mfma_f32_16x16x32_bf16(a[s8].v, bf1, acc1, 0, 0, 0);
        }
#pragma unroll
        for (int r = 0; r < 4; ++r) {
            p += qn0 * fast_tanh(acc0[r] + kb0);
            p += qn1 * fast_tanh(acc1[r] + kb1);
        }
    }
#pragma unroll
    for (int off = 32; off >= 1; off >>= 1) p += __shfl_down(p, off, 64);
    if (lane == 0) red[w] = p;
    __syncthreads();
    if (tid == 0) unsafeAtomicAdd(&score[slot], red[0] + red[1] + red[2] + red[3]);
}

// ---------------- 6. softmax over 2 metapath scores, blend, gather del_idx ----------
__global__ __launch_bounds__(256) void final_combine(const u16* __restrict__ out_ad,
                                                     const u16* __restrict__ out_dd,
                                                     const float* __restrict__ score,
                                                     const int* __restrict__ del_idx,
                                                     float* __restrict__ out) {
    int i = blockIdx.x;
    int f = threadIdx.x;
    int node = del_idx[i];
    float s0 = score[0] * (1.f / 20000.f);
    float s1 = score[1] * (1.f / 20000.f);
    float m = fmaxf(s0, s1);
    float e0 = __expf(s0 - m), e1 = __expf(s1 - m);
    float inv = 1.f / (e0 + e1);
    float a0 = e0 * inv, a1 = e1 * inv;
    float v0 = bf2f(out_ad[(size_t)node * 256 + f]); v0 = v0 > 0.f ? v0 : 0.f;
    float v1 = bf2f(out_dd[(size_t)node * 256 + f]); v1 = v1 > 0.f ? v1 : 0.f;
    out[(size_t)i * 256 + f] = a0 * v0 + a1 * v1;
}

extern "C" void kernel_launch(void* const* d_in, const int* in_sizes, int n_in,
                              void* d_out, int out_size, void* d_ws, size_t ws_size,
                              hipStream_t stream) {
    const float* x_add    = (const float*)d_in[0];
    const float* x_del    = (const float*)d_in[1];
    const float* W_add    = (const float*)d_in[2];
    const float* b_add    = (const float*)d_in[3];
    const float* W_del    = (const float*)d_in[4];
    const float* b_del    = (const float*)d_in[5];
    const float* att_ad_s = (const float*)d_in[6];
    const float* att_ad_d = (const float*)d_in[7];
    const float* att_dd_s = (const float*)d_in[12];
    const float* att_dd_d = (const float*)d_in[13];
    const float* k_W      = (const float*)d_in[14];
    const float* k_b      = (const float*)d_in[15];
    const float* q        = (const float*)d_in[16];
    const int* ei_ad      = (const int*)d_in[17];
    const int* ei_dd      = (const int*)d_in[20];
    const int* del_idx    = (const int*)d_in[21];
    float* out = (float*)d_out;

    const int N = 20000, E = 200000;
    char* ws = (char*)d_ws;
    size_t o = 0;
    // ---- zeroed region ----
    int* cnt_ad = (int*)(ws + o); o += (size_t)N * 4;
    int* cur_ad = (int*)(ws + o); o += (size_t)N * 4;
    int* cnt_dd = (int*)(ws + o); o += (size_t)N * 4;
    int* cur_dd = (int*)(ws + o); o += (size_t)N * 4;
    float* as_ad = (float*)(ws + o); o += (size_t)N * 2 * 4;
    float* ad_ad = (float*)(ws + o); o += (size_t)N * 2 * 4;
    float* as_dd = (float*)(ws + o); o += (size_t)N * 2 * 4;
    float* ad_dd = (float*)(ws + o); o += (size_t)N * 2 * 4;
    float* score = (float*)(ws + o); o += 256;
    size_t zero_bytes = o;
    // ---- written-once region ----
    u16* wb_add = (u16*)(ws + o); o += (size_t)256 * 768 * 2;
    u16* wb_del = (u16*)(ws + o); o += (size_t)256 * 768 * 2;
    u16* kwb    = (u16*)(ws + o); o += (size_t)256 * 256 * 2;
    int* off_ad = (int*)(ws + o); o += (size_t)(N + 1) * 4;
    int* off_dd = (int*)(ws + o); o += (size_t)(N + 1) * 4;
    int* srcs_ad = (int*)(ws + o); o += (size_t)E * 4;
    int* srcs_dd = (int*)(ws + o); o += (size_t)E * 4;
    u16* out_ad = (u16*)(ws + o); o += (size_t)N * 256 * 2;
    u16* out_dd = (u16*)(ws + o); o += (size_t)N * 256 * 2;
    u16* ha    = (u16*)(ws + o); o += (size_t)N * 256 * 2;
    u16* hd    = (u16*)(ws + o); o += (size_t)N * 256 * 2;

    hipMemsetAsync(d_ws, 0, zero_bytes, stream);

    // W/kW cvt + degree histogram, one dispatch
    prep_count<<<224 + (2 * E + 255) / 256, 256, 0, stream>>>(
        W_add, wb_add, W_del, wb_del, k_W, kwb, ei_ad, cnt_ad, ei_dd, cnt_dd, E);
    scan_two<<<2, 1024, 0, stream>>>(cnt_ad, off_ad, cnt_dd, off_dd, N);
    fill_csr2<<<(2 * E + 255) / 256, 256, 0, stream>>>(ei_ad, off_ad, cur_ad, srcs_ad,
                                                       ei_dd, off_dd, cur_dd, srcs_dd, E);

    // both projections (+ fused att-score dots): 626 blocks x 512 threads, single X pass
    gemm_h3<<<626, 512, 0, stream>>>(x_add, wb_add, b_add, ha,
                                     x_del, wb_del, b_del, hd,
                                     att_ad_s, att_ad_d, att_dd_s, att_dd_d,
                                     as_ad, ad_ad, as_dd, ad_dd, N);

    edge_gather2<<<10000, 256, 0, stream>>>(off_ad, srcs_ad, as_ad, ad_ad, ha, out_ad,
                                            off_dd, srcs_dd, as_dd, ad_dd, hd, out_dd, N);

    kgemm_score2<<<512, 256, 0, stream>>>(out_ad, out_dd, kwb, k_b, q, score);
    final_combine<<<4096, 256, 0, stream>>>(out_ad, out_dd, score, del_idx, out);
}

// Round 3
// 307.136 us; speedup vs baseline: 1.1488x; 1.0721x over previous
//
#include <hip/hip_runtime.h>
#include <hip/hip_bf16.h>

// HAN forward, del-branch only (add-branch _group output is unused in the reference).
// Inputs f32 / int32; output f32 [4096,256]. h and out_* stored bf16.
//
// R14:
//  - gemm_h3 kept verbatim (69 µs measured; byte-bound at ~11 B/cyc/CU L1-miss rate).
//  - fill_csr grafted into the gemm dispatch as extra blocks (independent work,
//    overlaps the latency-bound atomic-return cursors with gemm's memory streams,
//    removes one graph node).
//  - edge_gather3: one dst per 32 lanes, 16 B/lane uint4 gathers (half the VMEM
//    instructions), 4-edge unroll (4 independent gather chains).
//  - kgemm relu: branchless packed-u32 sign-mask trick (replaces 8 cmp+select per
//    uint4 with 4 ops/u32).

typedef unsigned short u16;
typedef __attribute__((ext_vector_type(8))) __bf16 bf16x8;
typedef __attribute__((ext_vector_type(4))) float f32x4;
typedef const __attribute__((address_space(1))) unsigned int* gu32p;
typedef __attribute__((address_space(3))) unsigned int* su32p;

__device__ inline float bf2f(u16 u) {
    union { unsigned int i; float f; } c; c.i = ((unsigned int)u) << 16; return c.f;
}
__device__ inline u16 f2bf(float f) {  // round-to-nearest-even
    union { float f; unsigned int i; } c; c.f = f;
    return (u16)((c.i + 0x7fffu + ((c.i >> 16) & 1u)) >> 16);
}
__device__ inline bf16x8 cvt8(f32x4 a, f32x4 b) {
    bf16x8 r;
    r[0] = (__bf16)a[0]; r[1] = (__bf16)a[1]; r[2] = (__bf16)a[2]; r[3] = (__bf16)a[3];
    r[4] = (__bf16)b[0]; r[5] = (__bf16)b[1]; r[6] = (__bf16)b[2]; r[7] = (__bf16)b[3];
    return r;
}
__device__ inline float fast_tanh(float x) {
    x = fminf(9.f, fmaxf(-9.f, x));
    float t = __expf(2.f * x);
    return (t - 1.f) / (t + 1.f);
}

// ---------------- 0. prep: W/kW f32->bf16 cvt + degree histogram (one dispatch) -----
__global__ __launch_bounds__(256) void prep_count(const float* __restrict__ W0, u16* __restrict__ wb0,
                                                  const float* __restrict__ W1, u16* __restrict__ wb1,
                                                  const float* __restrict__ kW, u16* __restrict__ kwb,
                                                  const int* __restrict__ eiA, int* __restrict__ cntA,
                                                  const int* __restrict__ eiB, int* __restrict__ cntB, int E) {
    int b = blockIdx.x;
    if (b < 224) {                        // 57344 chunks of 8 = W0|W1|kW exactly
        int idx = b * 256 + threadIdx.x;
        const float* s; u16* d; int i;
        if (idx < 24576)      { s = W0; d = wb0; i = idx; }
        else if (idx < 49152) { s = W1; d = wb1; i = idx - 24576; }
        else                  { s = kW; d = kwb; i = idx - 49152; }
        int e = i * 8;
        *(bf16x8*)(d + e) = cvt8(*(const f32x4*)(s + e), *(const f32x4*)(s + e + 4));
    } else {
        int idx = (b - 224) * 256 + threadIdx.x;
        int which = idx >= E;
        int e = idx - (which ? E : 0);
        if (e >= E) return;
        const int* ei = which ? eiB : eiA;
        int* cnt = which ? cntB : cntA;
        atomicAdd(&cnt[ei[E + e]], 1);
    }
}

// ---------------- 1. h = X @ W^T + b (+ fused att dots) [+ grafted CSR fill] --------
// Blocks 0..625: BM=64 BN=256 gemm (single X pass); 512 threads (8 waves, each 32x64).
//   A: reg-staged 512-B-per-row K-chunks, cvt->bf16, XOR-swizzled LDS dbuf.
//   B: global_load_lds triple-buffer, stored-swizzled, counted vmcnt.
// Blocks 626..1407: CSR fill (independent of gemm; overlaps its atomic latency).
__global__ __launch_bounds__(512, 4) void gemm_fill(
    const float* __restrict__ X0, const u16* __restrict__ Wb0,
    const float* __restrict__ b0, u16* __restrict__ H0,
    const float* __restrict__ X1, const u16* __restrict__ Wb1,
    const float* __restrict__ b1, u16* __restrict__ H1,
    const float* __restrict__ w_ads, const float* __restrict__ w_add,
    const float* __restrict__ w_dds, const float* __restrict__ w_ddd,
    float* __restrict__ as_ad, float* __restrict__ ad_ad,
    float* __restrict__ as_dd, float* __restrict__ ad_dd, int M,
    const int* __restrict__ eiA, const int* __restrict__ offA,
    int* __restrict__ curA, int* __restrict__ srcsA,
    const int* __restrict__ eiB, const int* __restrict__ offB,
    int* __restrict__ curB, int* __restrict__ srcsB, int E) {
    // LDS map (u16 units): A chunk dbuf 2 x 8192 (each 64 rows x 128 bf16, swizzled)
    //                      B slots 3 x 8192 at +16384 (each 256 rows x 32 bf16)
    __shared__ u16 lds[40960];           // 80 KB total -> 2 blocks/CU
    if (blockIdx.x >= 626) {             // ---- grafted CSR fill ----
        int idx = (int)(blockIdx.x - 626) * 512 + threadIdx.x;
        int whichE = idx >= E;
        int e = idx - (whichE ? E : 0);
        if (e < E) {
            const int* ei = whichE ? eiB : eiA;
            const int* off = whichE ? offB : offA;
            int* cursor = whichE ? curB : curA;
            int* srcs = whichE ? srcsB : srcsA;
            int s = ei[e], d = ei[E + e];
            int slot = off[d] + atomicAdd(&cursor[d], 1);
            srcs[slot] = s;
        }
        return;
    }
    int id = blockIdx.x;
    int which = id >= 313;
    int bm = which ? id - 313 : id;
    const float* X = which ? X1 : X0;
    const u16* Wb = which ? Wb1 : Wb0;
    const float* bias = which ? b1 : b0;
    u16* H = which ? H1 : H0;

    int tid = threadIdx.x;
    int w = tid >> 6, lane = tid & 63;
    int wrow = w & 1, wcol = w >> 1;     // wave tile: rows wrow*32..+32, cols wcol*64..+64
    int row16 = lane & 15, quad = lane >> 4;

// B tile kt -> slot: per wave 2 DMAs, 16 rows x 32 K bf16 each (stored-swizzled)
#define ISSUE_B(kt, slot) { \
    _Pragma("unroll") \
    for (int j = 0; j < 2; ++j) { \
        int rloc = (w * 2 + j) * 16 + (lane >> 2); \
        int cc = (lane & 3) ^ ((rloc >> 1) & 3); \
        const u16* gp = Wb + (size_t)rloc * 768 + (kt) * 32 + cc * 8; \
        u16* lp = lds + 16384 + (slot) * 8192 + (w * 2 + j) * 512; \
        __builtin_amdgcn_global_load_lds((gu32p)(const void*)gp, (su32p)(void*)lp, 16, 0, 0); \
    } }

// A chunk c: 64 rows x 128 f32; each wave-instruction covers 2 rows x 512 B contiguous
#define ALOAD(c, ar) { \
    _Pragma("unroll") \
    for (int i = 0; i < 4; ++i) { \
        int idx = i * 512 + tid; \
        int row = idx >> 5, col4 = idx & 31; \
        int rg = bm * 64 + row; if (rg > M - 1) rg = M - 1; \
        ar[i] = *(const f32x4*)(X + (size_t)rg * 768 + (c) * 128 + col4 * 4); \
    } }

// cvt->bf16 and XOR-swizzled store into A chunk buffer (c&1)
#define AWRITE(c, ar) { \
    _Pragma("unroll") \
    for (int i = 0; i < 4; ++i) { \
        int idx = i * 512 + tid; \
        int row = idx >> 5, col4 = idx & 31; \
        int off = ((c) & 1) * 8192 + row * 128 + (((col4 >> 1) ^ (row & 7)) << 3) + ((col4 & 1) << 2); \
        ushort4 v; v.x = f2bf(ar[i][0]); v.y = f2bf(ar[i][1]); v.z = f2bf(ar[i][2]); v.w = f2bf(ar[i][3]); \
        *(ushort4*)(lds + off) = v; \
    } }

#define STEP(ks) { \
    const int ksl = (ks) & 3, buf = ((ks) >> 2) & 1, slot = (ks) % 3; \
    bf16x8 af[2], bv[4]; \
    _Pragma("unroll") \
    for (int mi = 0; mi < 2; ++mi) { \
        int r = wrow * 32 + mi * 16 + row16; \
        af[mi] = *(const bf16x8*)(lds + buf * 8192 + r * 128 + (((ksl * 4 + quad) ^ (r & 7)) << 3)); \
    } \
    _Pragma("unroll") \
    for (int ni = 0; ni < 4; ++ni) { \
        int r = wcol * 64 + ni * 16 + row16; \
        bv[ni] = *(const bf16x8*)(lds + 16384 + slot * 8192 + r * 32 + ((quad ^ ((r >> 1) & 3)) << 3)); \
    } \
    _Pragma("unroll") \
    for (int mi = 0; mi < 2; ++mi) \
        _Pragma("unroll") \
        for (int ni = 0; ni < 4; ++ni) \
            acc[mi][ni] = __builtin_amdgcn_mfma_f32_16x16x32_bf16(af[mi], bv[ni], acc[mi][ni], 0, 0, 0); \
}

    f32x4 a0[4], a1[4];
    // prologue: B0,B1 DMAs; A chunks 0,1 loads; write chunk 0.
    ISSUE_B(0, 0)
    ISSUE_B(1, 1)
    ALOAD(0, a0)
    ALOAD(1, a1)
    asm volatile("s_waitcnt vmcnt(4)" ::: "memory");     // a0 done (drains B0,B1 too)
    AWRITE(0, a0)
    asm volatile("s_waitcnt lgkmcnt(0)" ::: "memory");
    asm volatile("s_barrier" ::: "memory");

    f32x4 acc[2][4] = {};
#pragma unroll
    for (int ks = 0; ks < 24; ++ks) {
        if (ks > 0) {
            // wait table (instruction-count vmcnt; B(ks) must be complete).
            const int wv = (ks == 23) ? 0 : (ks >= 17) ? 2 : ((ks & 2) ? 6 : 2);
            if (wv == 0)      asm volatile("s_waitcnt vmcnt(0) lgkmcnt(0)" ::: "memory");
            else if (wv == 2) asm volatile("s_waitcnt vmcnt(2) lgkmcnt(0)" ::: "memory");
            else              asm volatile("s_waitcnt vmcnt(6) lgkmcnt(0)" ::: "memory");
            asm volatile("s_barrier" ::: "memory");
        }
        if (ks < 22) ISSUE_B(ks + 2, (ks + 2) % 3)
        if (ks == 0) {
            asm volatile("s_waitcnt vmcnt(2)" ::: "memory"); // a1 done (B2 stays in flight)
            AWRITE(1, a1)
        } else if ((ks & 3) == 0 && ks <= 16) {
            AWRITE(ks / 4 + 1, a0)       // ks=4,8,12,16 -> chunks 2..5
        }
        if ((ks & 3) == 1 && ks <= 13) ALOAD(ks / 4 + 2, a0)  // ks=1,5,9,13 -> chunks 2..5
        STEP(ks)
    }
#undef ISSUE_B
#undef ALOAD
#undef AWRITE
#undef STEP

    // ---- epilogue: acc -> LDS bf16, coalesced store + fused att-score dots ----
    __syncthreads();
    u16* eps = lds;                      // 64 x 264 u16 = 33.8 KB
    const int SE2 = 264;
#pragma unroll
    for (int mi = 0; mi < 2; ++mi)
#pragma unroll
        for (int ni = 0; ni < 4; ++ni) {
            int col = wcol * 64 + ni * 16 + row16;
            float bvv = bias[col];
#pragma unroll
            for (int r = 0; r < 4; ++r)
                eps[(wrow * 32 + mi * 16 + quad * 4 + r) * SE2 + col] = f2bf(acc[mi][ni][r] + bvv);
        }
    __syncthreads();
    int mlim = M - bm * 64;
    int c0 = (tid & 31) * 8;             // 8 cols of the 256-col row; head = c0>>7
    int hh = c0 >> 7;
    float wv0[8], wv1[8], wv2[8];
    const float* att0 = which ? w_add : w_ads;
#pragma unroll
    for (int j = 0; j < 8; ++j) {
        wv0[j] = att0[c0 + j];
        wv1[j] = w_dds[c0 + j];
        wv2[j] = w_ddd[c0 + j];
    }
#pragma unroll
    for (int p = 0; p < 4; ++p) {
        int row = p * 16 + (tid >> 5);
        union { uint4 q; u16 s[8]; } v;
        v.q = *(const uint4*)(eps + row * SE2 + c0);
        if (row < mlim)
            *(uint4*)(H + (size_t)(bm * 64 + row) * 256 + c0) = v.q;
        float d0 = 0.f, d1 = 0.f, d2 = 0.f;
#pragma unroll
        for (int j = 0; j < 8; ++j) {
            float hv = bf2f(v.s[j]);
            d0 += hv * wv0[j];
            if (which) { d1 += hv * wv1[j]; d2 += hv * wv2[j]; }
        }
#pragma unroll
        for (int off = 8; off >= 1; off >>= 1) {
            d0 += __shfl_down(d0, off, 16);
            if (which) { d1 += __shfl_down(d1, off, 16); d2 += __shfl_down(d2, off, 16); }
        }
        if ((tid & 15) == 0 && row < mlim) {
            int n = bm * 64 + row;
            if (!which) {
                unsafeAtomicAdd(&as_ad[n * 2 + hh], d0);
            } else {
                unsafeAtomicAdd(&ad_ad[n * 2 + hh], d0);
                unsafeAtomicAdd(&as_dd[n * 2 + hh], d1);
                unsafeAtomicAdd(&ad_dd[n * 2 + hh], d2);
            }
        }
    }
}

// ---------------- 3b. exclusive scan, int4-blocked ----------------------------------
__global__ __launch_bounds__(1024) void scan_two(const int* __restrict__ cntA, int* __restrict__ offA,
                                                 const int* __restrict__ cntB, int* __restrict__ offB, int n) {
    const int* cnt = blockIdx.x ? cntB : cntA;
    int* off = blockIdx.x ? offB : offA;
    __shared__ int wsum[16];
    __shared__ int woff[16];
    __shared__ int tot_s;
    __shared__ int carry_s;
    int tid = threadIdx.x, wid = tid >> 6, lane = tid & 63;
    if (tid == 0) carry_s = 0;
    __syncthreads();
    for (int base = 0; base < n; base += 4096) {
        int i = base + tid * 4;
        int v0 = (i + 0 < n) ? cnt[i + 0] : 0;
        int v1 = (i + 1 < n) ? cnt[i + 1] : 0;
        int v2 = (i + 2 < n) ? cnt[i + 2] : 0;
        int v3 = (i + 3 < n) ? cnt[i + 3] : 0;
        int s0 = v0, s1 = s0 + v1, s2 = s1 + v2, s3 = s2 + v3;
        int x = s3;
#pragma unroll
        for (int d = 1; d < 64; d <<= 1) {
            int t = __shfl_up(x, d, 64);
            if (lane >= d) x += t;
        }
        if (lane == 63) wsum[wid] = x;
        __syncthreads();
        if (wid == 0) {
            int s = (lane < 16) ? wsum[lane] : 0;
#pragma unroll
            for (int d = 1; d < 16; d <<= 1) {
                int t = __shfl_up(s, d, 64);
                if (lane >= d) s += t;
            }
            if (lane < 16) woff[lane] = s - wsum[lane];
            if (lane == 15) tot_s = s;
        }
        __syncthreads();
        int basev = carry_s + woff[wid] + (x - s3);
        if (i + 0 < n) off[i + 0] = basev;
        if (i + 1 < n) off[i + 1] = basev + s0;
        if (i + 2 < n) off[i + 2] = basev + s1;
        if (i + 3 < n) off[i + 3] = basev + s2;
        __syncthreads();
        if (tid == 0) carry_s += tot_s;
    }
    __syncthreads();
    if (tid == 0) off[n] = carry_s;
}

// ---------------- 4. gather: one dst per 32 lanes, 16 B/lane, 4-edge unroll ---------
__global__ __launch_bounds__(256) void edge_gather3(const int* __restrict__ offA, const int* __restrict__ srcsA,
                                                    const float* __restrict__ asA, const float* __restrict__ adA,
                                                    const u16* __restrict__ hA, u16* __restrict__ outA,
                                                    const int* __restrict__ offB, const int* __restrict__ srcsB,
                                                    const float* __restrict__ asB, const float* __restrict__ adB,
                                                    const u16* __restrict__ hB, u16* __restrict__ outB, int N) {
    int gid = blockIdx.x * 256 + threadIdx.x;
    int grp = gid >> 5;                  // one 32-lane group per dst node
    int which = grp >= N;
    int d = grp - (which ? N : 0);
    if (d >= N) return;
    const int* off = which ? offB : offA;
    const int* srcs = which ? srcsB : srcsA;
    const float* a_src = which ? asB : asA;
    const float* a_dst = which ? adB : adA;
    const u16* h = which ? hB : hA;
    u16* out = which ? outB : outA;
    int l = gid & 31;
    int hh = l >> 4;                     // cols 0-127 head0, 128-255 head1
    int f = l * 8;                       // 8 bf16 = 16 B per lane
    float ad0 = a_dst[d * 2 + hh];
    int beg = off[d], end = off[d + 1];
    float acc[8] = {0.f, 0.f, 0.f, 0.f, 0.f, 0.f, 0.f, 0.f};
    float S = 0.f;
    union U8 { uint4 q; u16 s[8]; };
    int p = beg;
    for (; p + 4 <= end; p += 4) {       // 4 independent gather chains in flight
        int s0 = srcs[p], s1 = srcs[p + 1], s2 = srcs[p + 2], s3 = srcs[p + 3];
        U8 x0, x1, x2, x3;
        x0.q = *(const uint4*)(h + (size_t)s0 * 256 + f);
        x1.q = *(const uint4*)(h + (size_t)s1 * 256 + f);
        x2.q = *(const uint4*)(h + (size_t)s2 * 256 + f);
        x3.q = *(const uint4*)(h + (size_t)s3 * 256 + f);
        float v0 = a_src[s0 * 2 + hh] + ad0;
        float v1 = a_src[s1 * 2 + hh] + ad0;
        float v2 = a_src[s2 * 2 + hh] + ad0;
        float v3 = a_src[s3 * 2 + hh] + ad0;
        v0 = v0 > 0.f ? v0 : 0.2f * v0;
        v1 = v1 > 0.f ? v1 : 0.2f * v1;
        v2 = v2 > 0.f ? v2 : 0.2f * v2;
        v3 = v3 > 0.f ? v3 : 0.2f * v3;
        float e0 = __expf(v0), e1 = __expf(v1), e2 = __expf(v2), e3 = __expf(v3);
        S += (e0 + e1) + (e2 + e3);
#pragma unroll
        for (int j = 0; j < 8; ++j)
            acc[j] += e0 * bf2f(x0.s[j]) + e1 * bf2f(x1.s[j]) + e2 * bf2f(x2.s[j]) + e3 * bf2f(x3.s[j]);
    }
    for (; p < end; ++p) {
        int s0 = srcs[p];
        U8 x0; x0.q = *(const uint4*)(h + (size_t)s0 * 256 + f);
        float v0 = a_src[s0 * 2 + hh] + ad0;
        v0 = v0 > 0.f ? v0 : 0.2f * v0;
        float e0 = __expf(v0);
        S += e0;
#pragma unroll
        for (int j = 0; j < 8; ++j) acc[j] += e0 * bf2f(x0.s[j]);
    }
    float inv = 1.f / (S + 1e-16f);
    union U8 o;
#pragma unroll
    for (int j = 0; j < 8; ++j) o.s[j] = f2bf(acc[j] * inv);
    *(uint4*)(out + (size_t)d * 256 + f) = o.q;
}

// ---------------- 5. semantic scores; A bf16, kW pre-converted bf16 -----------------
#define SK 264
__global__ __launch_bounds__(256) void kgemm_score2(const u16* __restrict__ outA,
                                                    const u16* __restrict__ outB,
                                                    const u16* __restrict__ kwb,
                                                    const float* __restrict__ kb,
                                                    const float* __restrict__ qv,
                                                    float* __restrict__ score) {
    __shared__ u16 Bs[128 * SK];          // 66 KB
    __shared__ float red[4];
    int slot = blockIdx.x >> 8;           // 0..1
    int b = blockIdx.x & 255;
    const u16* outm = slot ? outB : outA;
    int bn = b & 1;
    int bidx = b >> 1;                    // 0..127
    int tid = threadIdx.x;
    int w = tid >> 6, lane = tid & 63;
    int row16 = lane & 15, quad = lane >> 4;

#pragma unroll
    for (int i = 0; i < 16; ++i) {
        int c = tid + 256 * i;
        int r = c >> 5, col8 = (c & 31) * 8;
        *(bf16x8*)(Bs + r * SK + col8) = *(const bf16x8*)(kwb + (size_t)(bn * 128 + r) * 256 + col8);
    }
    __syncthreads();

    float kb0 = kb[bn * 128 + w * 32 + row16];
    float qn0 = qv[bn * 128 + w * 32 + row16];
    float kb1 = kb[bn * 128 + w * 32 + 16 + row16];
    float qn1 = qv[bn * 128 + w * 32 + 16 + row16];
    const u16* b0 = Bs + (w * 32 + row16) * SK + quad * 8;
    const u16* b1 = Bs + (w * 32 + 16 + row16) * SK + quad * 8;

    union U { uint4 q; unsigned int u[4]; u16 s[8]; bf16x8 v; };
    float p = 0.f;
    for (int mt = bidx; mt < 1250; mt += 128) {
        const u16* arow = outm + (size_t)(mt * 16 + row16) * 256 + quad * 8;
        U a[8];
#pragma unroll
        for (int s8 = 0; s8 < 8; ++s8) a[s8].q = *(const uint4*)(arow + s8 * 32);
        f32x4 acc0 = {0.f,0.f,0.f,0.f}, acc1 = {0.f,0.f,0.f,0.f};
#pragma unroll
        for (int s8 = 0; s8 < 8; ++s8) {
#pragma unroll
            for (int u = 0; u < 4; ++u) { // relu in bf16 domain, branchless packed
                unsigned int x = a[s8].u[u];
                unsigned int sg = x & 0x80008000u;
                unsigned int m = sg | (sg - (sg >> 15));
                a[s8].u[u] = x & ~m;
            }
            bf16x8 bf0 = *(const bf16x8*)(b0 + s8 * 32);
            bf16x8 bf1 = *(const bf16x8*)(b1 + s8 * 32);
            acc0 = __builtin_amdgcn_mfma_f32_16x16x32_bf16(a[s8].v, bf0, acc0, 0, 0, 0);
            acc1 = __builtin_amdgcn_mfma_f32_16x16x32_bf16(a[s8].v, bf1, acc1, 0, 0, 0);
        }
#pragma unroll
        for (int r = 0; r < 4; ++r) {
            p += qn0 * fast_tanh(acc0[r] + kb0);
            p += qn1 * fast_tanh(acc1[r] + kb1);
        }
    }
#pragma unroll
    for (int off = 32; off >= 1; off >>= 1) p += __shfl_down(p, off, 64);
    if (lane == 0) red[w] = p;
    __syncthreads();
    if (tid == 0) unsafeAtomicAdd(&score[slot], red[0] + red[1] + red[2] + red[3]);
}

// ---------------- 6. softmax over 2 metapath scores, blend, gather del_idx ----------
__global__ __launch_bounds__(256) void final_combine(const u16* __restrict__ out_ad,
                                                     const u16* __restrict__ out_dd,
                                                     const float* __restrict__ score,
                                                     const int* __restrict__ del_idx,
                                                     float* __restrict__ out) {
    int i = blockIdx.x;
    int f = threadIdx.x;
    int node = del_idx[i];
    float s0 = score[0] * (1.f / 20000.f);
    float s1 = score[1] * (1.f / 20000.f);
    float m = fmaxf(s0, s1);
    float e0 = __expf(s0 - m), e1 = __expf(s1 - m);
    float inv = 1.f / (e0 + e1);
    float a0 = e0 * inv, a1 = e1 * inv;
    float v0 = bf2f(out_ad[(size_t)node * 256 + f]); v0 = v0 > 0.f ? v0 : 0.f;
    float v1 = bf2f(out_dd[(size_t)node * 256 + f]); v1 = v1 > 0.f ? v1 : 0.f;
    out[(size_t)i * 256 + f] = a0 * v0 + a1 * v1;
}

extern "C" void kernel_launch(void* const* d_in, const int* in_sizes, int n_in,
                              void* d_out, int out_size, void* d_ws, size_t ws_size,
                              hipStream_t stream) {
    const float* x_add    = (const float*)d_in[0];
    const float* x_del    = (const float*)d_in[1];
    const float* W_add    = (const float*)d_in[2];
    const float* b_add    = (const float*)d_in[3];
    const float* W_del    = (const float*)d_in[4];
    const float* b_del    = (const float*)d_in[5];
    const float* att_ad_s = (const float*)d_in[6];
    const float* att_ad_d = (const float*)d_in[7];
    const float* att_dd_s = (const float*)d_in[12];
    const float* att_dd_d = (const float*)d_in[13];
    const float* k_W      = (const float*)d_in[14];
    const float* k_b      = (const float*)d_in[15];
    const float* q        = (const float*)d_in[16];
    const int* ei_ad      = (const int*)d_in[17];
    const int* ei_dd      = (const int*)d_in[20];
    const int* del_idx    = (const int*)d_in[21];
    float* out = (float*)d_out;

    const int N = 20000, E = 200000;
    char* ws = (char*)d_ws;
    size_t o = 0;
    // ---- zeroed region ----
    int* cnt_ad = (int*)(ws + o); o += (size_t)N * 4;
    int* cur_ad = (int*)(ws + o); o += (size_t)N * 4;
    int* cnt_dd = (int*)(ws + o); o += (size_t)N * 4;
    int* cur_dd = (int*)(ws + o); o += (size_t)N * 4;
    float* as_ad = (float*)(ws + o); o += (size_t)N * 2 * 4;
    float* ad_ad = (float*)(ws + o); o += (size_t)N * 2 * 4;
    float* as_dd = (float*)(ws + o); o += (size_t)N * 2 * 4;
    float* ad_dd = (float*)(ws + o); o += (size_t)N * 2 * 4;
    float* score = (float*)(ws + o); o += 256;
    size_t zero_bytes = o;
    // ---- written-once region ----
    u16* wb_add = (u16*)(ws + o); o += (size_t)256 * 768 * 2;
    u16* wb_del = (u16*)(ws + o); o += (size_t)256 * 768 * 2;
    u16* kwb    = (u16*)(ws + o); o += (size_t)256 * 256 * 2;
    int* off_ad = (int*)(ws + o); o += (size_t)(N + 1) * 4;
    int* off_dd = (int*)(ws + o); o += (size_t)(N + 1) * 4;
    int* srcs_ad = (int*)(ws + o); o += (size_t)E * 4;
    int* srcs_dd = (int*)(ws + o); o += (size_t)E * 4;
    u16* out_ad = (u16*)(ws + o); o += (size_t)N * 256 * 2;
    u16* out_dd = (u16*)(ws + o); o += (size_t)N * 256 * 2;
    u16* ha    = (u16*)(ws + o); o += (size_t)N * 256 * 2;
    u16* hd    = (u16*)(ws + o); o += (size_t)N * 256 * 2;

    hipMemsetAsync(d_ws, 0, zero_bytes, stream);

    // W/kW cvt + degree histogram, one dispatch
    prep_count<<<224 + (2 * E + 255) / 256, 256, 0, stream>>>(
        W_add, wb_add, W_del, wb_del, k_W, kwb, ei_ad, cnt_ad, ei_dd, cnt_dd, E);
    scan_two<<<2, 1024, 0, stream>>>(cnt_ad, off_ad, cnt_dd, off_dd, N);

    // gemm (626 blocks) + grafted CSR fill (782 blocks), one dispatch
    gemm_fill<<<626 + (2 * E + 511) / 512, 512, 0, stream>>>(
        x_add, wb_add, b_add, ha,
        x_del, wb_del, b_del, hd,
        att_ad_s, att_ad_d, att_dd_s, att_dd_d,
        as_ad, ad_ad, as_dd, ad_dd, N,
        ei_ad, off_ad, cur_ad, srcs_ad,
        ei_dd, off_dd, cur_dd, srcs_dd, E);

    // gather: 40000 dst groups x 32 lanes
    edge_gather3<<<(2 * N * 32 + 255) / 256, 256, 0, stream>>>(
        off_ad, srcs_ad, as_ad, ad_ad, ha, out_ad,
        off_dd, srcs_dd, as_dd, ad_dd, hd, out_dd, N);

    kgemm_score2<<<512, 256, 0, stream>>>(out_ad, out_dd, kwb, k_b, q, score);
    final_combine<<<4096, 256, 0, stream>>>(out_ad, out_dd, score, del_idx, out);
}

// Round 5
// 290.218 us; speedup vs baseline: 1.2158x; 1.0583x over previous
//
#include <hip/hip_runtime.h>
#include <hip/hip_bf16.h>

// HAN forward, del-branch only (add-branch _group output is unused in the reference).
// Inputs f32 / int32; output f32 [4096,256]. h and out_* stored bf16.
//
// R15 (resubmit; previous round hit GPUAcquisitionTimeout, no data):
//  - Single-pass bucketed CSR (cap 48; Poisson(10) ⇒ P(deg≥48)≈1e-17): deletes
//    scan_two dispatch, deletes the histogram pass, deletes the fill graft from
//    the gemm dispatch (R14 showed the graft ran as a +22 µs serial LDS-bound tail).
//    prep_fill = W/kW cvt blocks + edge scatter blocks, one dispatch, no LDS.
//  - gemm_h3 restored verbatim (verified 69 µs; byte-bound at ~11 B/cyc/CU L1 port).
//  - edge_gather4: bucket CSR lets the 4-edge src batch be one aligned int4 load.

typedef unsigned short u16;
typedef __attribute__((ext_vector_type(8))) __bf16 bf16x8;
typedef __attribute__((ext_vector_type(4))) float f32x4;
typedef const __attribute__((address_space(1))) unsigned int* gu32p;
typedef __attribute__((address_space(3))) unsigned int* su32p;

#define CAP 48   // bucket capacity per dst node

__device__ inline float bf2f(u16 u) {
    union { unsigned int i; float f; } c; c.i = ((unsigned int)u) << 16; return c.f;
}
__device__ inline u16 f2bf(float f) {  // round-to-nearest-even
    union { float f; unsigned int i; } c; c.f = f;
    return (u16)((c.i + 0x7fffu + ((c.i >> 16) & 1u)) >> 16);
}
__device__ inline bf16x8 cvt8(f32x4 a, f32x4 b) {
    bf16x8 r;
    r[0] = (__bf16)a[0]; r[1] = (__bf16)a[1]; r[2] = (__bf16)a[2]; r[3] = (__bf16)a[3];
    r[4] = (__bf16)b[0]; r[5] = (__bf16)b[1]; r[6] = (__bf16)b[2]; r[7] = (__bf16)b[3];
    return r;
}
__device__ inline float fast_tanh(float x) {
    x = fminf(9.f, fmaxf(-9.f, x));
    float t = __expf(2.f * x);
    return (t - 1.f) / (t + 1.f);
}

// ---------------- 0. prep: W/kW cvt + single-pass bucketed CSR fill -----------------
__global__ __launch_bounds__(256) void prep_fill(const float* __restrict__ W0, u16* __restrict__ wb0,
                                                 const float* __restrict__ W1, u16* __restrict__ wb1,
                                                 const float* __restrict__ kW, u16* __restrict__ kwb,
                                                 const int* __restrict__ eiA, int* __restrict__ cntA,
                                                 int* __restrict__ srcsA,
                                                 const int* __restrict__ eiB, int* __restrict__ cntB,
                                                 int* __restrict__ srcsB, int E) {
    int b = blockIdx.x;
    if (b < 224) {                        // 57344 chunks of 8 = W0|W1|kW exactly
        int idx = b * 256 + threadIdx.x;
        const float* s; u16* d; int i;
        if (idx < 24576)      { s = W0; d = wb0; i = idx; }
        else if (idx < 49152) { s = W1; d = wb1; i = idx - 24576; }
        else                  { s = kW; d = kwb; i = idx - 49152; }
        int e = i * 8;
        *(bf16x8*)(d + e) = cvt8(*(const f32x4*)(s + e), *(const f32x4*)(s + e + 4));
    } else {                              // bucketed CSR scatter, one atomic pass
        int idx = (b - 224) * 256 + threadIdx.x;
        int which = idx >= E;
        int e = idx - (which ? E : 0);
        if (e >= E) return;
        const int* ei = which ? eiB : eiA;
        int* cnt = which ? cntB : cntA;
        int* srcs = which ? srcsB : srcsA;
        int s = ei[e], d = ei[E + e];
        int slot = atomicAdd(&cnt[d], 1);
        if (slot < CAP) srcs[d * CAP + slot] = s;
    }
}

// ---------------- 1. h = X @ W^T + b (+ fused attention-score dots) -----------------
// BM=64 BN=256 (single X pass); 626 blocks x 512 threads (8 waves, each 32x64).
// A: reg-staged 512-B-per-row K-chunks (128 f32), cvt->bf16, XOR-swizzled LDS dbuf.
// B: global_load_lds triple-buffer, stored-swizzled, counted vmcnt (no mid-loop drain).
__global__ __launch_bounds__(512, 4) void gemm_h3(
    const float* __restrict__ X0, const u16* __restrict__ Wb0,
    const float* __restrict__ b0, u16* __restrict__ H0,
    const float* __restrict__ X1, const u16* __restrict__ Wb1,
    const float* __restrict__ b1, u16* __restrict__ H1,
    const float* __restrict__ w_ads, const float* __restrict__ w_add,
    const float* __restrict__ w_dds, const float* __restrict__ w_ddd,
    float* __restrict__ as_ad, float* __restrict__ ad_ad,
    float* __restrict__ as_dd, float* __restrict__ ad_dd, int M) {
    // LDS map (u16 units): A chunk dbuf 2 x 8192 (each 64 rows x 128 bf16, swizzled)
    //                      B slots 3 x 8192 at +16384 (each 256 rows x 32 bf16)
    __shared__ u16 lds[40960];           // 80 KB total -> 2 blocks/CU
    int id = blockIdx.x;
    int which = id >= 313;
    int bm = which ? id - 313 : id;
    const float* X = which ? X1 : X0;
    const u16* Wb = which ? Wb1 : Wb0;
    const float* bias = which ? b1 : b0;
    u16* H = which ? H1 : H0;

    int tid = threadIdx.x;
    int w = tid >> 6, lane = tid & 63;
    int wrow = w & 1, wcol = w >> 1;     // wave tile: rows wrow*32..+32, cols wcol*64..+64
    int row16 = lane & 15, quad = lane >> 4;

// B tile kt -> slot: per wave 2 DMAs, 16 rows x 32 K bf16 each (stored-swizzled)
#define ISSUE_B(kt, slot) { \
    _Pragma("unroll") \
    for (int j = 0; j < 2; ++j) { \
        int rloc = (w * 2 + j) * 16 + (lane >> 2); \
        int cc = (lane & 3) ^ ((rloc >> 1) & 3); \
        const u16* gp = Wb + (size_t)rloc * 768 + (kt) * 32 + cc * 8; \
        u16* lp = lds + 16384 + (slot) * 8192 + (w * 2 + j) * 512; \
        __builtin_amdgcn_global_load_lds((gu32p)(const void*)gp, (su32p)(void*)lp, 16, 0, 0); \
    } }

// A chunk c: 64 rows x 128 f32; each wave-instruction covers 2 rows x 512 B contiguous
#define ALOAD(c, ar) { \
    _Pragma("unroll") \
    for (int i = 0; i < 4; ++i) { \
        int idx = i * 512 + tid; \
        int row = idx >> 5, col4 = idx & 31; \
        int rg = bm * 64 + row; if (rg > M - 1) rg = M - 1; \
        ar[i] = *(const f32x4*)(X + (size_t)rg * 768 + (c) * 128 + col4 * 4); \
    } }

// cvt->bf16 and XOR-swizzled store into A chunk buffer (c&1)
#define AWRITE(c, ar) { \
    _Pragma("unroll") \
    for (int i = 0; i < 4; ++i) { \
        int idx = i * 512 + tid; \
        int row = idx >> 5, col4 = idx & 31; \
        int off = ((c) & 1) * 8192 + row * 128 + (((col4 >> 1) ^ (row & 7)) << 3) + ((col4 & 1) << 2); \
        ushort4 v; v.x = f2bf(ar[i][0]); v.y = f2bf(ar[i][1]); v.z = f2bf(ar[i][2]); v.w = f2bf(ar[i][3]); \
        *(ushort4*)(lds + off) = v; \
    } }

#define STEP(ks) { \
    const int ksl = (ks) & 3, buf = ((ks) >> 2) & 1, slot = (ks) % 3; \
    bf16x8 af[2], bv[4]; \
    _Pragma("unroll") \
    for (int mi = 0; mi < 2; ++mi) { \
        int r = wrow * 32 + mi * 16 + row16; \
        af[mi] = *(const bf16x8*)(lds + buf * 8192 + r * 128 + (((ksl * 4 + quad) ^ (r & 7)) << 3)); \
    } \
    _Pragma("unroll") \
    for (int ni = 0; ni < 4; ++ni) { \
        int r = wcol * 64 + ni * 16 + row16; \
        bv[ni] = *(const bf16x8*)(lds + 16384 + slot * 8192 + r * 32 + ((quad ^ ((r >> 1) & 3)) << 3)); \
    } \
    _Pragma("unroll") \
    for (int mi = 0; mi < 2; ++mi) \
        _Pragma("unroll") \
        for (int ni = 0; ni < 4; ++ni) \
            acc[mi][ni] = __builtin_amdgcn_mfma_f32_16x16x32_bf16(af[mi], bv[ni], acc[mi][ni], 0, 0, 0); \
}

    f32x4 a0[4], a1[4];
    // prologue: B0,B1 DMAs; A chunks 0,1 loads; write chunk 0.
    ISSUE_B(0, 0)
    ISSUE_B(1, 1)
    ALOAD(0, a0)
    ALOAD(1, a1)
    asm volatile("s_waitcnt vmcnt(4)" ::: "memory");     // a0 done (drains B0,B1 too)
    AWRITE(0, a0)
    asm volatile("s_waitcnt lgkmcnt(0)" ::: "memory");
    asm volatile("s_barrier" ::: "memory");

    f32x4 acc[2][4] = {};
#pragma unroll
    for (int ks = 0; ks < 24; ++ks) {
        if (ks > 0) {
            // wait table (instruction-count vmcnt; B(ks) must be complete).
            const int wv = (ks == 23) ? 0 : (ks >= 17) ? 2 : ((ks & 2) ? 6 : 2);
            if (wv == 0)      asm volatile("s_waitcnt vmcnt(0) lgkmcnt(0)" ::: "memory");
            else if (wv == 2) asm volatile("s_waitcnt vmcnt(2) lgkmcnt(0)" ::: "memory");
            else              asm volatile("s_waitcnt vmcnt(6) lgkmcnt(0)" ::: "memory");
            asm volatile("s_barrier" ::: "memory");
        }
        if (ks < 22) ISSUE_B(ks + 2, (ks + 2) % 3)
        if (ks == 0) {
            asm volatile("s_waitcnt vmcnt(2)" ::: "memory"); // a1 done (B2 stays in flight)
            AWRITE(1, a1)
        } else if ((ks & 3) == 0 && ks <= 16) {
            AWRITE(ks / 4 + 1, a0)       // ks=4,8,12,16 -> chunks 2..5
        }
        if ((ks & 3) == 1 && ks <= 13) ALOAD(ks / 4 + 2, a0)  // ks=1,5,9,13 -> chunks 2..5
        STEP(ks)
    }
#undef ISSUE_B
#undef ALOAD
#undef AWRITE
#undef STEP

    // ---- epilogue: acc -> LDS bf16, coalesced store + fused att-score dots ----
    __syncthreads();
    u16* eps = lds;                      // 64 x 264 u16 = 33.8 KB
    const int SE2 = 264;
#pragma unroll
    for (int mi = 0; mi < 2; ++mi)
#pragma unroll
        for (int ni = 0; ni < 4; ++ni) {
            int col = wcol * 64 + ni * 16 + row16;
            float bvv = bias[col];
#pragma unroll
            for (int r = 0; r < 4; ++r)
                eps[(wrow * 32 + mi * 16 + quad * 4 + r) * SE2 + col] = f2bf(acc[mi][ni][r] + bvv);
        }
    __syncthreads();
    int mlim = M - bm * 64;
    int c0 = (tid & 31) * 8;             // 8 cols of the 256-col row; head = c0>>7
    int hh = c0 >> 7;
    float wv0[8], wv1[8], wv2[8];
    const float* att0 = which ? w_add : w_ads;
#pragma unroll
    for (int j = 0; j < 8; ++j) {
        wv0[j] = att0[c0 + j];
        wv1[j] = w_dds[c0 + j];
        wv2[j] = w_ddd[c0 + j];
    }
#pragma unroll
    for (int p = 0; p < 4; ++p) {
        int row = p * 16 + (tid >> 5);
        union { uint4 q; u16 s[8]; } v;
        v.q = *(const uint4*)(eps + row * SE2 + c0);
        if (row < mlim)
            *(uint4*)(H + (size_t)(bm * 64 + row) * 256 + c0) = v.q;
        float d0 = 0.f, d1 = 0.f, d2 = 0.f;
#pragma unroll
        for (int j = 0; j < 8; ++j) {
            float hv = bf2f(v.s[j]);
            d0 += hv * wv0[j];
            if (which) { d1 += hv * wv1[j]; d2 += hv * wv2[j]; }
        }
#pragma unroll
        for (int off = 8; off >= 1; off >>= 1) {
            d0 += __shfl_down(d0, off, 16);
            if (which) { d1 += __shfl_down(d1, off, 16); d2 += __shfl_down(d2, off, 16); }
        }
        if ((tid & 15) == 0 && row < mlim) {
            int n = bm * 64 + row;
            if (!which) {
                unsafeAtomicAdd(&as_ad[n * 2 + hh], d0);
            } else {
                unsafeAtomicAdd(&ad_ad[n * 2 + hh], d0);
                unsafeAtomicAdd(&as_dd[n * 2 + hh], d1);
                unsafeAtomicAdd(&ad_dd[n * 2 + hh], d2);
            }
        }
    }
}

// ---------------- 4. gather: one dst per 32 lanes, 16 B/lane, int4 src batch --------
__global__ __launch_bounds__(256) void edge_gather4(const int* __restrict__ cntA, const int* __restrict__ srcsA,
                                                    const float* __restrict__ asA, const float* __restrict__ adA,
                                                    const u16* __restrict__ hA, u16* __restrict__ outA,
                                                    const int* __restrict__ cntB, const int* __restrict__ srcsB,
                                                    const float* __restrict__ asB, const float* __restrict__ adB,
                                                    const u16* __restrict__ hB, u16* __restrict__ outB, int N) {
    int gid = blockIdx.x * 256 + threadIdx.x;
    int grp = gid >> 5;                  // one 32-lane group per dst node
    int which = grp >= N;
    int d = grp - (which ? N : 0);
    if (d >= N) return;
    const int* cnt = which ? cntB : cntA;
    const int* srcs = which ? srcsB : srcsA;
    const float* a_src = which ? asB : asA;
    const float* a_dst = which ? adB : adA;
    const u16* h = which ? hB : hA;
    u16* out = which ? outB : outA;
    int l = gid & 31;
    int hh = l >> 4;                     // cols 0-127 head0, 128-255 head1
    int f = l * 8;                       // 8 bf16 = 16 B per lane
    float ad0 = a_dst[d * 2 + hh];
    int deg = cnt[d]; if (deg > CAP) deg = CAP;
    const int* sp = srcs + d * CAP;      // 16B-aligned (CAP*4 = 192 B)
    float acc[8] = {0.f, 0.f, 0.f, 0.f, 0.f, 0.f, 0.f, 0.f};
    float S = 0.f;
    union U8 { uint4 q; u16 s[8]; };
    int p = 0;
    for (; p + 4 <= deg; p += 4) {       // 4 independent gather chains in flight
        int4 s4 = *(const int4*)(sp + p);
        U8 x0, x1, x2, x3;
        x0.q = *(const uint4*)(h + (size_t)s4.x * 256 + f);
        x1.q = *(const uint4*)(h + (size_t)s4.y * 256 + f);
        x2.q = *(const uint4*)(h + (size_t)s4.z * 256 + f);
        x3.q = *(const uint4*)(h + (size_t)s4.w * 256 + f);
        float v0 = a_src[s4.x * 2 + hh] + ad0;
        float v1 = a_src[s4.y * 2 + hh] + ad0;
        float v2 = a_src[s4.z * 2 + hh] + ad0;
        float v3 = a_src[s4.w * 2 + hh] + ad0;
        v0 = v0 > 0.f ? v0 : 0.2f * v0;
        v1 = v1 > 0.f ? v1 : 0.2f * v1;
        v2 = v2 > 0.f ? v2 : 0.2f * v2;
        v3 = v3 > 0.f ? v3 : 0.2f * v3;
        float e0 = __expf(v0), e1 = __expf(v1), e2 = __expf(v2), e3 = __expf(v3);
        S += (e0 + e1) + (e2 + e3);
#pragma unroll
        for (int j = 0; j < 8; ++j)
            acc[j] += e0 * bf2f(x0.s[j]) + e1 * bf2f(x1.s[j]) + e2 * bf2f(x2.s[j]) + e3 * bf2f(x3.s[j]);
    }
    for (; p < deg; ++p) {
        int s0 = sp[p];
        U8 x0; x0.q = *(const uint4*)(h + (size_t)s0 * 256 + f);
        float v0 = a_src[s0 * 2 + hh] + ad0;
        v0 = v0 > 0.f ? v0 : 0.2f * v0;
        float e0 = __expf(v0);
        S += e0;
#pragma unroll
        for (int j = 0; j < 8; ++j) acc[j] += e0 * bf2f(x0.s[j]);
    }
    float inv = 1.f / (S + 1e-16f);
    union U8 o;
#pragma unroll
    for (int j = 0; j < 8; ++j) o.s[j] = f2bf(acc[j] * inv);
    *(uint4*)(out + (size_t)d * 256 + f) = o.q;
}

// ---------------- 5. semantic scores; A bf16, kW pre-converted bf16 -----------------
#define SK 264
__global__ __launch_bounds__(256) void kgemm_score2(const u16* __restrict__ outA,
                                                    const u16* __restrict__ outB,
                                                    const u16* __restrict__ kwb,
                                                    const float* __restrict__ kb,
                                                    const float* __restrict__ qv,
                                                    float* __restrict__ score) {
    __shared__ u16 Bs[128 * SK];          // 66 KB
    __shared__ float red[4];
    int slot = blockIdx.x >> 8;           // 0..1
    int b = blockIdx.x & 255;
    const u16* outm = slot ? outB : outA;
    int bn = b & 1;
    int bidx = b >> 1;                    // 0..127
    int tid = threadIdx.x;
    int w = tid >> 6, lane = tid & 63;
    int row16 = lane & 15, quad = lane >> 4;

#pragma unroll
    for (int i = 0; i < 16; ++i) {
        int c = tid + 256 * i;
        int r = c >> 5, col8 = (c & 31) * 8;
        *(bf16x8*)(Bs + r * SK + col8) = *(const bf16x8*)(kwb + (size_t)(bn * 128 + r) * 256 + col8);
    }
    __syncthreads();

    float kb0 = kb[bn * 128 + w * 32 + row16];
    float qn0 = qv[bn * 128 + w * 32 + row16];
    float kb1 = kb[bn * 128 + w * 32 + 16 + row16];
    float qn1 = qv[bn * 128 + w * 32 + 16 + row16];
    const u16* b0 = Bs + (w * 32 + row16) * SK + quad * 8;
    const u16* b1 = Bs + (w * 32 + 16 + row16) * SK + quad * 8;

    union U { uint4 q; unsigned int u[4]; u16 s[8]; bf16x8 v; };
    float p = 0.f;
    for (int mt = bidx; mt < 1250; mt += 128) {
        const u16* arow = outm + (size_t)(mt * 16 + row16) * 256 + quad * 8;
        U a[8];
#pragma unroll
        for (int s8 = 0; s8 < 8; ++s8) a[s8].q = *(const uint4*)(arow + s8 * 32);
        f32x4 acc0 = {0.f,0.f,0.f,0.f}, acc1 = {0.f,0.f,0.f,0.f};
#pragma unroll
        for (int s8 = 0; s8 < 8; ++s8) {
#pragma unroll
            for (int u = 0; u < 4; ++u) { // relu in bf16 domain, branchless packed
                unsigned int x = a[s8].u[u];
                unsigned int sg = x & 0x80008000u;
                unsigned int m = sg | (sg - (sg >> 15));
                a[s8].u[u] = x & ~m;
            }
            bf16x8 bf0 = *(const bf16x8*)(b0 + s8 * 32);
            bf16x8 bf1 = *(const bf16x8*)(b1 + s8 * 32);
            acc0 = __builtin_amdgcn_mfma_f32_16x16x32_bf16(a[s8].v, bf0, acc0, 0, 0, 0);
            acc1 = __builtin_amdgcn_mfma_f32_16x16x32_bf16(a[s8].v, bf1, acc1, 0, 0, 0);
        }
#pragma unroll
        for (int r = 0; r < 4; ++r) {
            p += qn0 * fast_tanh(acc0[r] + kb0);
            p += qn1 * fast_tanh(acc1[r] + kb1);
        }
    }
#pragma unroll
    for (int off = 32; off >= 1; off >>= 1) p += __shfl_down(p, off, 64);
    if (lane == 0) red[w] = p;
    __syncthreads();
    if (tid == 0) unsafeAtomicAdd(&score[slot], red[0] + red[1] + red[2] + red[3]);
}

// ---------------- 6. softmax over 2 metapath scores, blend, gather del_idx ----------
__global__ __launch_bounds__(256) void final_combine(const u16* __restrict__ out_ad,
                                                     const u16* __restrict__ out_dd,
                                                     const float* __restrict__ score,
                                                     const int* __restrict__ del_idx,
                                                     float* __restrict__ out) {
    int i = blockIdx.x;
    int f = threadIdx.x;
    int node = del_idx[i];
    float s0 = score[0] * (1.f / 20000.f);
    float s1 = score[1] * (1.f / 20000.f);
    float m = fmaxf(s0, s1);
    float e0 = __expf(s0 - m), e1 = __expf(s1 - m);
    float inv = 1.f / (e0 + e1);
    float a0 = e0 * inv, a1 = e1 * inv;
    float v0 = bf2f(out_ad[(size_t)node * 256 + f]); v0 = v0 > 0.f ? v0 : 0.f;
    float v1 = bf2f(out_dd[(size_t)node * 256 + f]); v1 = v1 > 0.f ? v1 : 0.f;
    out[(size_t)i * 256 + f] = a0 * v0 + a1 * v1;
}

extern "C" void kernel_launch(void* const* d_in, const int* in_sizes, int n_in,
                              void* d_out, int out_size, void* d_ws, size_t ws_size,
                              hipStream_t stream) {
    const float* x_add    = (const float*)d_in[0];
    const float* x_del    = (const float*)d_in[1];
    const float* W_add    = (const float*)d_in[2];
    const float* b_add    = (const float*)d_in[3];
    const float* W_del    = (const float*)d_in[4];
    const float* b_del    = (const float*)d_in[5];
    const float* att_ad_s = (const float*)d_in[6];
    const float* att_ad_d = (const float*)d_in[7];
    const float* att_dd_s = (const float*)d_in[12];
    const float* att_dd_d = (const float*)d_in[13];
    const float* k_W      = (const float*)d_in[14];
    const float* k_b      = (const float*)d_in[15];
    const float* q        = (const float*)d_in[16];
    const int* ei_ad      = (const int*)d_in[17];
    const int* ei_dd      = (const int*)d_in[20];
    const int* del_idx    = (const int*)d_in[21];
    float* out = (float*)d_out;

    const int N = 20000, E = 200000;
    char* ws = (char*)d_ws;
    size_t o = 0;
    // ---- zeroed region ----
    int* cnt_ad = (int*)(ws + o); o += (size_t)N * 4;
    int* cnt_dd = (int*)(ws + o); o += (size_t)N * 4;
    float* as_ad = (float*)(ws + o); o += (size_t)N * 2 * 4;
    float* ad_ad = (float*)(ws + o); o += (size_t)N * 2 * 4;
    float* as_dd = (float*)(ws + o); o += (size_t)N * 2 * 4;
    float* ad_dd = (float*)(ws + o); o += (size_t)N * 2 * 4;
    float* score = (float*)(ws + o); o += 256;
    size_t zero_bytes = o;
    // ---- written-once region ----
    u16* wb_add = (u16*)(ws + o); o += (size_t)256 * 768 * 2;
    u16* wb_del = (u16*)(ws + o); o += (size_t)256 * 768 * 2;
    u16* kwb    = (u16*)(ws + o); o += (size_t)256 * 256 * 2;
    int* srcs_ad = (int*)(ws + o); o += (size_t)N * CAP * 4;
    int* srcs_dd = (int*)(ws + o); o += (size_t)N * CAP * 4;
    u16* out_ad = (u16*)(ws + o); o += (size_t)N * 256 * 2;
    u16* out_dd = (u16*)(ws + o); o += (size_t)N * 256 * 2;
    u16* ha    = (u16*)(ws + o); o += (size_t)N * 256 * 2;
    u16* hd    = (u16*)(ws + o); o += (size_t)N * 256 * 2;

    hipMemsetAsync(d_ws, 0, zero_bytes, stream);

    // W/kW cvt + single-pass bucketed CSR fill, one dispatch
    prep_fill<<<224 + (2 * E + 255) / 256, 256, 0, stream>>>(
        W_add, wb_add, W_del, wb_del, k_W, kwb,
        ei_ad, cnt_ad, srcs_ad, ei_dd, cnt_dd, srcs_dd, E);

    // both projections (+ fused att-score dots): 626 blocks x 512 threads, single X pass
    gemm_h3<<<626, 512, 0, stream>>>(x_add, wb_add, b_add, ha,
                                     x_del, wb_del, b_del, hd,
                                     att_ad_s, att_ad_d, att_dd_s, att_dd_d,
                                     as_ad, ad_ad, as_dd, ad_dd, N);

    // gather: 40000 dst groups x 32 lanes
    edge_gather4<<<(2 * N * 32 + 255) / 256, 256, 0, stream>>>(
        cnt_ad, srcs_ad, as_ad, ad_ad, ha, out_ad,
        cnt_dd, srcs_dd, as_dd, ad_dd, hd, out_dd, N);

    kgemm_score2<<<512, 256, 0, stream>>>(out_ad, out_dd, kwb, k_b, q, score);
    final_combine<<<4096, 256, 0, stream>>>(out_ad, out_dd, score, del_idx, out);
}